// Round 13
// baseline (340.893 us; speedup 1.0000x reference)
//
#include <hip/hip_runtime.h>
#include <math.h>

// Problem constants
#define Bdim 32
#define Ndim 2048
#define Cdim 3
#define Kdim 20
#define Edim 64
#define NPART 27                 // 6 first moments + 21 second moments
#define NBLK1 2048               // k1 grid = 64 x 32
#define CNT (Bdim * Ndim * Kdim) // BN sample count = 1,310,720

#define NEG_INF __int_as_float(0xFF800000)

// Wave reduces via __builtin_amdgcn_update_dpp (mov_dpp + op). VERIFIED in
// R4/R5/R7/R8/R10/R11/R12. R9's inline-asm fused-DPP version FAILED
// correctness — builtins only.
#define DPPU(v, ctrl) \
  ((unsigned)__builtin_amdgcn_update_dpp((int)(v), (int)(v), (ctrl), 0xf, 0xf, false))
#define DPPF(v, ctrl) \
  (__int_as_float(__builtin_amdgcn_update_dpp(__float_as_int(v), __float_as_int(v), (ctrl), 0xf, 0xf, false)))

// PER-HALF max: first 5 steps of the verified 6-step chain. After row_ror
// 1/2/4/8 every 16-row holds its row max; row_bcast15 then gives
// lane31 = max(lanes 0..31) and lane63 = max(lanes 32..63) (bcast15 reads
// OLD lane47, so point-A state cannot leak into lane63 — transitively
// verified: the 6-step chain's final step consumes exactly these values).
__device__ __forceinline__ float red_max_f32_halves(float v) {
  float t;
  t = DPPF(v, 0x121); v = fmaxf(v, t);  // row_ror:1
  t = DPPF(v, 0x122); v = fmaxf(v, t);  // row_ror:2
  t = DPPF(v, 0x124); v = fmaxf(v, t);  // row_ror:4
  t = DPPF(v, 0x128); v = fmaxf(v, t);  // row_ror:8
  t = DPPF(v, 0x142); v = fmaxf(v, t);  // row_bcast15 -> lane31/lane63 half max
  return v;
}

__device__ __forceinline__ unsigned red_max_u32_halves(unsigned v) {
  unsigned t;
  t = DPPU(v, 0x121); v = (v > t) ? v : t;
  t = DPPU(v, 0x122); v = (v > t) ? v : t;
  t = DPPU(v, 0x124); v = (v > t) ? v : t;
  t = DPPU(v, 0x128); v = (v > t) ? v : t;
  t = DPPU(v, 0x142); v = (v > t) ? v : t;  // lane31 / lane63 per-half max
  return v;
}

// Wave-wide sum; result valid in lane 63 only (verified 6-step chain).
__device__ __forceinline__ float red_add_f32_l63(float v) {
  float t;
  t = DPPF(v, 0x121); v += t;
  t = DPPF(v, 0x122); v += t;
  t = DPPF(v, 0x124); v += t;
  t = DPPF(v, 0x128); v += t;
  t = DPPF(v, 0x142); v += t;
  t = DPPF(v, 0x143); v += t;
  return v;
}

__device__ __forceinline__ float sreadf(float v, int l) {
  return __int_as_float(__builtin_amdgcn_readlane(__float_as_int(v), l));
}

// ---------------------------------------------------------------------------
// Kernel 1: KNN top-20 per point + 27 edge-moment partial sums per block.
// 512 threads = 8 waves sharing one pts[] copy. R13: HALF-WAVE points —
// each wave runs 2 passes of 2 points; lanes 0-31 own point A, 32-63 own
// point B (64 candidates/lane, j = t*32 + (lane&31), u64 consumed mask).
// One 5-step per-half DPP reduce + one ballot serves BOTH points per round,
// halving the serial chain and per-point round issue vs R11 (which measured
// 190 us). State stays SCALAR (R8/R10: array state collapses occupancy
// 71->42%). R12 (always-on 12-step u32 reduce) regressed 190->224 — keep the
// dual-singleton ballot fast path, u32 reduce only as tie fallback.
// !!! DISTANCE EXPRESSION IS FROZEN: `dot = pi.x*pj.x + pi.y*pj.y + pi.z*pj.z;
// pd = 2.0f*dot - pi.w - pj.w` — R6: any re-association flips near-tie
// selections vs the np reference and fails the absmax threshold.
// ---------------------------------------------------------------------------
__global__ __launch_bounds__(512) void k1_knn_stats(
    const float* __restrict__ xyz, int* __restrict__ idx_out,
    float* __restrict__ partials) {
  __shared__ float4 pts[Ndim];       // {x, y, z, ||p||^2}  (32 KiB)
  __shared__ float red[8][NPART];

  const int b = blockIdx.y;
  const int tid = threadIdx.x;
  const float* xb = xyz + (size_t)b * Ndim * Cdim;

  // Stage xyz[b] into LDS
  float* sp = (float*)&pts[0];
  for (int g = tid; g < Ndim * Cdim; g += 512) {
    sp[(g / 3) * 4 + (g % 3)] = xb[g];
  }
  __syncthreads();
  for (int p = tid; p < Ndim; p += 512) {
    float4 q = pts[p];
    pts[p].w = q.x * q.x + q.y * q.y + q.z * q.z;
  }
  __syncthreads();

  const int w = tid >> 6;
  const int lane = tid & 63;
  const int half = lane >> 5;          // 0: point A, 1: point B
  const int hl = lane & 31;

  float acc[NPART];
#pragma unroll
  for (int c = 0; c < NPART; ++c) acc[c] = 0.0f;

  const int i0 = blockIdx.x * 32 + w * 4;

  for (int q = 0; q < 2; ++q) {
    const int i = i0 + 2 * q + half;   // this lane's point
    const float4 pi = pts[i];

    unsigned long long mask = 0ull;    // bit t -> slot j = t*32+hl consumed
    float h1 = NEG_INF, h2 = NEG_INF, h3 = NEG_INF;
    unsigned l1 = 0u, l2 = 0u, l3 = 0u;   // slot index t (0..63)

    // Initial top-3 scan: 64 candidates per lane (halves read same addrs ->
    // LDS broadcast, no extra conflicts)
#pragma unroll 8
    for (int t = 0; t < 64; ++t) {
      const int j = t * 32 + hl;
      const float4 pj = pts[j];
      const float dot = pi.x * pj.x + pi.y * pj.y + pi.z * pj.z;
      const float pd = 2.0f * dot - pi.w - pj.w;   // (FROZEN)
      const bool b1 = pd > h1;
      const bool b2 = pd > h2;
      const bool b3 = pd > h3;
      h3 = b3 ? (b2 ? h2 : pd) : h3;  l3 = b3 ? (b2 ? l2 : (unsigned)t) : l3;
      h2 = b2 ? (b1 ? h1 : pd) : h2;  l2 = b2 ? (b1 ? l1 : (unsigned)t) : l2;
      h1 = b1 ? pd : h1;              l1 = b1 ? (unsigned)t : l1;
    }

    unsigned myJ = 0u;
    for (int r = 0; r < Kdim; ++r) {
      // 1) per-half max of heads: ONE 5-step DPP chain for both points
      const float bm = red_max_f32_halves(h1);
      const float bkA = sreadf(bm, 31);
      const float bkB = sreadf(bm, 63);
      const float bestk = half ? bkB : bkA;

      // 2) winners per half: ballot; dual-singleton fast path
      const unsigned long long mb = __ballot(h1 == bestk);
      const unsigned lo = (unsigned)mb;
      const unsigned hi = (unsigned)(mb >> 32);
      unsigned jwinA, jwinB;
      if (((lo & (lo - 1u)) | (hi & (hi - 1u))) == 0u) {  // both singleton
        const int wlA = __ffs(lo) - 1;
        const int wlB = 32 + __ffs(hi) - 1;
        jwinA = ((unsigned)__builtin_amdgcn_readlane((int)l1, wlA)) * 32u +
                (unsigned)wlA;
        jwinB = ((unsigned)__builtin_amdgcn_readlane((int)l1, wlB)) * 32u +
                ((unsigned)wlB & 31u);
      } else {                                            // tie (rare)
        unsigned cand =
            (h1 == bestk) ? (2047u - (l1 * 32u + (unsigned)hl)) : 0u;
        cand = red_max_u32_halves(cand);
        jwinA = 2047u - (unsigned)__builtin_amdgcn_readlane((int)cand, 31);
        jwinB = 2047u - (unsigned)__builtin_amdgcn_readlane((int)cand, 63);
      }
      const unsigned jwin = half ? jwinB : jwinA;
      myJ = ((unsigned)hl == (unsigned)r) ? jwin : myJ;

      // 3) branchless owner-pop; rescan branch kept (rare: lane's 4th win)
      const bool win = ((unsigned)hl == (jwin & 31u));
      const bool pop = win && (h2 != NEG_INF);
      const bool resc = win && (h2 == NEG_INF);
      mask |= win ? (1ull << (jwin >> 5)) : 0ull;
      h1 = pop ? h2 : h1;  l1 = pop ? l2 : l1;
      h2 = pop ? h3 : h2;  l2 = pop ? l3 : l2;
      h3 = pop ? NEG_INF : h3;
      if (resc) {
        float a1 = NEG_INF, a2 = NEG_INF, a3 = NEG_INF;
        unsigned c1 = 0u, c2 = 0u, c3 = 0u;
        for (int t = 0; t < 64; ++t) {
          if (mask & (1ull << t)) continue;
          const int j = t * 32 + hl;
          const float4 pj = pts[j];
          const float dot = pi.x * pj.x + pi.y * pj.y + pi.z * pj.z;
          const float pd = 2.0f * dot - pi.w - pj.w;   // (FROZEN)
          const bool b1 = pd > a1;
          const bool b2 = pd > a2;
          const bool b3 = pd > a3;
          a3 = b3 ? (b2 ? a2 : pd) : a3;  c3 = b3 ? (b2 ? c2 : (unsigned)t) : c3;
          a2 = b2 ? (b1 ? a1 : pd) : a2;  c2 = b2 ? (b1 ? c1 : (unsigned)t) : c2;
          a1 = b1 ? pd : a1;              c1 = b1 ? (unsigned)t : c1;
        }
        h1 = a1; l1 = c1; h2 = a2; l2 = c2; h3 = a3; l3 = c3;
      }
    }

    // Epilogue: both halves store their point's indices + edge moments
    if (hl < Kdim) {
      idx_out[((size_t)b * Ndim + i) * Kdim + hl] = (int)myJ;
      const float4 pj = pts[myJ];
      float ev[6];
      ev[0] = pi.x; ev[1] = pi.y; ev[2] = pi.z;
      ev[3] = pj.x - pi.x; ev[4] = pj.y - pi.y; ev[5] = pj.z - pi.z;
#pragma unroll
      for (int a = 0; a < 6; ++a) acc[a] += ev[a];
      int c = 6;
#pragma unroll
      for (int a = 0; a < 6; ++a)
#pragma unroll
        for (int d = a; d < 6; ++d) { acc[c] += ev[a] * ev[d]; ++c; }
    }
  }

  // Block reduction of the 27 accumulators (verified 6-step DPP adds;
  // lane63 = sum over all 64 lanes = both halves' contributions)
#pragma unroll
  for (int c = 0; c < NPART; ++c) {
    const float v = red_add_f32_l63(acc[c]);
    if (lane == 63) red[w][c] = v;
  }
  __syncthreads();
  if (tid < NPART) {
    const int bid = blockIdx.y * gridDim.x + blockIdx.x;
    float v = 0.0f;
#pragma unroll
    for (int qq = 0; qq < 8; ++qq) v += red[qq][tid];
    partials[(size_t)bid * NPART + tid] = v;
  }
}

// ---------------------------------------------------------------------------
// Kernel 2: reduce 2048 partials (f64), fold 6x6 moments through W into
// per-channel BN scale/shift.
// ---------------------------------------------------------------------------
__global__ __launch_bounds__(256) void k2_bnstats(
    const float* __restrict__ partials, const float* __restrict__ W,
    const float* __restrict__ gamma, const float* __restrict__ beta,
    float* __restrict__ ss) {
  __shared__ double stat[NPART];
  __shared__ double red[4];
  const int tid = threadIdx.x;
  const int lane = tid & 63;
  const int w = tid >> 6;

  for (int c = 0; c < NPART; ++c) {
    double v = 0.0;
    for (int p = tid; p < NBLK1; p += 256) v += (double)partials[(size_t)p * NPART + c];
#pragma unroll
    for (int d = 1; d < 64; d <<= 1) v += __shfl_xor(v, d, 64);
    if (lane == 0) red[w] = v;
    __syncthreads();
    if (tid == 0) stat[c] = red[0] + red[1] + red[2] + red[3];
    __syncthreads();
  }

  if (tid < Edim) {
    const double inv = 1.0 / (double)CNT;
    double mu[6];
#pragma unroll
    for (int c = 0; c < 6; ++c) mu[c] = stat[c] * inv;
    double wv[6];
#pragma unroll
    for (int c = 0; c < 6; ++c) wv[c] = (double)W[tid * 6 + c];
    double m = 0.0;
#pragma unroll
    for (int c = 0; c < 6; ++c) m += wv[c] * mu[c];
    double q = 0.0;
    int s = 6;
#pragma unroll
    for (int a = 0; a < 6; ++a)
#pragma unroll
      for (int d = a; d < 6; ++d) {
        q += (a == d ? 1.0 : 2.0) * wv[a] * wv[d] * (stat[s] * inv);
        ++s;
      }
    const double var = q - m * m;
    const double rstd = 1.0 / sqrt(var + 1e-5);
    const float scale = (float)((double)gamma[tid] * rstd);
    const float shift = (float)((double)beta[tid] - m * rstd * (double)gamma[tid]);
    ss[tid] = scale;
    ss[Edim + tid] = shift;
  }
}

// ---------------------------------------------------------------------------
// Kernel 3: recompute h per (b,n,k,e), BN + hardswish, max over k, write
// out[b,e,n] coalesced via LDS transpose. 512 threads; lane = channel e.
// Neighbor index is wave-uniform -> readfirstlane enables scalar loads.
// (verified passing in R8/R10/R11/R12)
// ---------------------------------------------------------------------------
__global__ __launch_bounds__(512) void k3_out(
    const float* __restrict__ xyz, const int* __restrict__ idx,
    const float* __restrict__ W, const float* __restrict__ ss,
    float* __restrict__ out) {
  __shared__ float4 pts[Ndim];   // 32 KiB: {x,y,z,unused}
  __shared__ float sm[128][65];  // 33 KiB
  const int b = blockIdx.y;
  const int n0 = blockIdx.x * 128;
  const int tid = threadIdx.x;
  const int w = tid >> 6;
  const int lane = tid & 63;
  const float* xb = xyz + (size_t)b * Ndim * Cdim;

  float* sp = (float*)&pts[0];
  for (int g = tid; g < Ndim * Cdim; g += 512) {
    sp[(g / 3) * 4 + (g % 3)] = xb[g];
  }
  __syncthreads();

  float wv[6];
#pragma unroll
  for (int c = 0; c < 6; ++c) wv[c] = W[lane * 6 + c];
  const float scale = ss[lane];
  const float shift = ss[Edim + lane];

  for (int s = 0; s < 16; ++s) {
    const int i = n0 + w * 16 + s;
    const float4 pi = pts[i];
    const float hbase = wv[0] * pi.x + wv[1] * pi.y + wv[2] * pi.z;
    const int* ip = idx + ((size_t)b * Ndim + i) * Kdim;
    float m = -INFINITY;
    for (int k = 0; k < Kdim; ++k) {
      const int j = __builtin_amdgcn_readfirstlane(ip[k]);
      const float4 pj = pts[j];
      const float h = hbase + wv[3] * (pj.x - pi.x) + wv[4] * (pj.y - pi.y) +
                      wv[5] * (pj.z - pi.z);
      const float a = h * scale + shift;
      const float r6 = fminf(fmaxf(a + 3.0f, 0.0f), 6.0f);
      const float hs = a * r6 * (1.0f / 6.0f);
      m = fmaxf(m, hs);
    }
    sm[w * 16 + s][lane] = m;
  }
  __syncthreads();

#pragma unroll
  for (int r = 0; r < 8; ++r) {
    const int e = r * 8 + w;
    out[((size_t)b * Edim + e) * Ndim + n0 + lane] = sm[lane][e];
    out[((size_t)b * Edim + e) * Ndim + n0 + 64 + lane] = sm[64 + lane][e];
  }
}

// ---------------------------------------------------------------------------
extern "C" void kernel_launch(void* const* d_in, const int* in_sizes, int n_in,
                              void* d_out, int out_size, void* d_ws, size_t ws_size,
                              hipStream_t stream) {
  const float* xyz = (const float*)d_in[0];
  const float* W = (const float*)d_in[1];
  const float* gamma = (const float*)d_in[2];
  const float* beta = (const float*)d_in[3];
  float* out = (float*)d_out;

  char* ws = (char*)d_ws;
  int* idx = (int*)ws;                                        // 5,242,880 B
  float* partials = (float*)(ws + (size_t)Bdim * Ndim * Kdim * 4);
  float* ss = (float*)(ws + (size_t)Bdim * Ndim * Kdim * 4 + (size_t)NBLK1 * NPART * 4);

  // Output 0: xyz passthrough
  hipMemcpyAsync(out, xyz, (size_t)Bdim * Ndim * Cdim * sizeof(float),
                 hipMemcpyDeviceToDevice, stream);

  k1_knn_stats<<<dim3(Ndim / 32, Bdim), 512, 0, stream>>>(xyz, idx, partials);
  k2_bnstats<<<1, 256, 0, stream>>>(partials, W, gamma, beta, ss);
  k3_out<<<dim3(Ndim / 128, Bdim), 512, 0, stream>>>(
      xyz, idx, W, ss, out + (size_t)Bdim * Ndim * Cdim);
}

// Round 14
// 254.033 us; speedup vs baseline: 1.3419x; 1.3419x over previous
//
#include <hip/hip_runtime.h>
#include <math.h>

// Problem constants
#define Bdim 32
#define Ndim 2048
#define Cdim 3
#define Kdim 20
#define Edim 64
#define NPART 27                 // 6 first moments + 21 second moments
#define NBLK1 2048               // k1 grid = 64 x 32
#define CNT (Bdim * Ndim * Kdim) // BN sample count = 1,310,720

#define NEG_INF __int_as_float(0xFF800000)

// Wave reduces via __builtin_amdgcn_update_dpp (mov_dpp + op). VERIFIED in
// R4/R5/R7/R8/R10/R11. R9's inline-asm fused-DPP version FAILED correctness —
// do not replace without a standalone lane-exact A/B.
#define DPPU(v, ctrl) \
  ((unsigned)__builtin_amdgcn_update_dpp((int)(v), (int)(v), (ctrl), 0xf, 0xf, false))
#define DPPF(v, ctrl) \
  (__int_as_float(__builtin_amdgcn_update_dpp(__float_as_int(v), __float_as_int(v), (ctrl), 0xf, 0xf, false)))

// Wave-wide max (u32); result valid in lane 63.
__device__ __forceinline__ unsigned red_max_u32_l63(unsigned v) {
  unsigned t;
  t = DPPU(v, 0x121); v = (v > t) ? v : t;  // row_ror:1
  t = DPPU(v, 0x122); v = (v > t) ? v : t;  // row_ror:2
  t = DPPU(v, 0x124); v = (v > t) ? v : t;  // row_ror:4
  t = DPPU(v, 0x128); v = (v > t) ? v : t;  // row_ror:8
  t = DPPU(v, 0x142); v = (v > t) ? v : t;  // row_bcast15
  t = DPPU(v, 0x143); v = (v > t) ? v : t;  // row_bcast31 -> lane63 global
  return v;
}

// Wave-wide max (f32, finite values + NEG_INF sentinel); result in lane 63.
__device__ __forceinline__ float red_max_f32_l63(float v) {
  float t;
  t = DPPF(v, 0x121); v = fmaxf(v, t);
  t = DPPF(v, 0x122); v = fmaxf(v, t);
  t = DPPF(v, 0x124); v = fmaxf(v, t);
  t = DPPF(v, 0x128); v = fmaxf(v, t);
  t = DPPF(v, 0x142); v = fmaxf(v, t);
  t = DPPF(v, 0x143); v = fmaxf(v, t);
  return v;
}

// Wave-wide sum; result valid in lane 63 only.
__device__ __forceinline__ float red_add_f32_l63(float v) {
  float t;
  t = DPPF(v, 0x121); v += t;
  t = DPPF(v, 0x122); v += t;
  t = DPPF(v, 0x124); v += t;
  t = DPPF(v, 0x128); v += t;
  t = DPPF(v, 0x142); v += t;
  t = DPPF(v, 0x143); v += t;
  return v;
}

__device__ __forceinline__ float sreadf(float v, int l) {
  return __int_as_float(__builtin_amdgcn_readlane(__float_as_int(v), l));
}

// ---------------------------------------------------------------------------
// Kernel 1: KNN top-20 per point + 27 edge-moment partial sums per block.
// R7/R11 structure — the session's verified optimum (k1 = 190 us, VGPR 32,
// occupancy 71% = HW max for 33 KB LDS): 512 threads = 8 waves sharing one
// pts[] copy; each wave handles 4 points SEQUENTIALLY with scalar state.
// A/B-REFUTED neighborhood — do not reintroduce any of these:
//  * R8  fused scan + fused rounds:       292 us (occ 42%)
//  * R10 fused scan + sequential rounds:  295 us (occ 42%) — array state
//        itself collapses occupancy; time tracks occupancy (latency-bound)
//  * R12 branch-free always-reduce winner: 224 us (+25 serial VALU/round;
//        the ballot/ffs SALU path co-issues and was never the bottleneck)
//  * R13 half-wave points (5-step chains): 278 us (occ 54%, cross-half
//        select overhead)
//  * R9 inline-asm fused-DPP reduces: WRONG RESULTS. Builtins only.
// !!! DISTANCE EXPRESSION IS FROZEN: `dot = pi.x*pj.x + pi.y*pj.y + pi.z*pj.z;
// pd = 2.0f*dot - pi.w - pj.w` — R6 showed any re-association flips near-tie
// selections vs the np reference and fails the absmax threshold.
// ---------------------------------------------------------------------------
__global__ __launch_bounds__(512) void k1_knn_stats(
    const float* __restrict__ xyz, int* __restrict__ idx_out,
    float* __restrict__ partials) {
  __shared__ float4 pts[Ndim];       // {x, y, z, ||p||^2}  (32 KiB)
  __shared__ float red[8][NPART];

  const int b = blockIdx.y;
  const int tid = threadIdx.x;
  const float* xb = xyz + (size_t)b * Ndim * Cdim;

  // Stage xyz[b] into LDS
  float* sp = (float*)&pts[0];
  for (int g = tid; g < Ndim * Cdim; g += 512) {
    sp[(g / 3) * 4 + (g % 3)] = xb[g];
  }
  __syncthreads();
  for (int p = tid; p < Ndim; p += 512) {
    float4 q = pts[p];
    pts[p].w = q.x * q.x + q.y * q.y + q.z * q.z;
  }
  __syncthreads();

  const int w = tid >> 6;
  const int lane = tid & 63;

  float acc[NPART];
#pragma unroll
  for (int c = 0; c < NPART; ++c) acc[c] = 0.0f;

  for (int s = 0; s < 4; ++s) {
    const int i = blockIdx.x * 32 + w * 4 + s;
    const float4 pi = pts[i];

    unsigned mask = 0u;                   // bit t -> slot j = t*64+lane consumed
    float h1 = NEG_INF, h2 = NEG_INF, h3 = NEG_INF;
    unsigned l1 = 0u, l2 = 0u, l3 = 0u;   // slot index t

    // Initial top-3 scan over this lane's 32 candidates
#pragma unroll 8
    for (int t = 0; t < 32; ++t) {
      const int j = t * 64 + lane;
      const float4 pj = pts[j];
      const float dot = pi.x * pj.x + pi.y * pj.y + pi.z * pj.z;
      const float pd = 2.0f * dot - pi.w - pj.w;   // (FROZEN)
      const bool b1 = pd > h1;
      const bool b2 = pd > h2;
      const bool b3 = pd > h3;
      h3 = b3 ? (b2 ? h2 : pd) : h3;  l3 = b3 ? (b2 ? l2 : (unsigned)t) : l3;
      h2 = b2 ? (b1 ? h1 : pd) : h2;  l2 = b2 ? (b1 ? l1 : (unsigned)t) : l2;
      h1 = b1 ? pd : h1;              l1 = b1 ? (unsigned)t : l1;
    }

    unsigned myJ = 0u;
    for (int r = 0; r < Kdim; ++r) {
      // 1) global max of heads (f32, exact), builtin-DPP VALU reduce
      const float bm = red_max_f32_l63(h1);
      const float bestk = sreadf(bm, 63);

      // 2) winner: ballot of head==best; exact tie -> max (2047-j)
      const unsigned long long mb = __ballot(h1 == bestk);
      unsigned jwin;
      if ((mb & (mb - 1ull)) == 0ull) {            // single owner (common)
        const int wl = __ffsll((unsigned long long)mb) - 1;
        jwin = ((unsigned)__builtin_amdgcn_readlane((int)l1, wl)) * 64u +
               (unsigned)wl;
      } else {                                      // exact tie (rare), uniform
        unsigned cand =
            (h1 == bestk) ? (2047u - (l1 * 64u + (unsigned)lane)) : 0u;
        cand = red_max_u32_l63(cand);
        jwin = 2047u - (unsigned)__builtin_amdgcn_readlane((int)cand, 63);
      }
      if (lane == r) myJ = jwin;

      // 3) owner lane pops: mark consumed, promote, or rescan on 3rd win
      if ((unsigned)lane == (jwin & 63u)) {
        mask |= (1u << (jwin >> 6));
        if (h2 != NEG_INF) {
          h1 = h2; l1 = l2; h2 = h3; l2 = l3; h3 = NEG_INF;
        } else {
          float a1 = NEG_INF, a2 = NEG_INF, a3 = NEG_INF;
          unsigned c1 = 0u, c2 = 0u, c3 = 0u;
          for (int t = 0; t < 32; ++t) {
            if (mask & (1u << t)) continue;
            const int j = t * 64 + lane;
            const float4 pj = pts[j];
            const float dot = pi.x * pj.x + pi.y * pj.y + pi.z * pj.z;
            const float pd = 2.0f * dot - pi.w - pj.w;   // (FROZEN)
            const bool b1 = pd > a1;
            const bool b2 = pd > a2;
            const bool b3 = pd > a3;
            a3 = b3 ? (b2 ? a2 : pd) : a3;  c3 = b3 ? (b2 ? c2 : (unsigned)t) : c3;
            a2 = b2 ? (b1 ? a1 : pd) : a2;  c2 = b2 ? (b1 ? c1 : (unsigned)t) : c2;
            a1 = b1 ? pd : a1;              c1 = b1 ? (unsigned)t : c1;
          }
          h1 = a1; l1 = c1; h2 = a2; l2 = c2; h3 = a3; l3 = c3;
        }
      }
    }

    if (lane < Kdim) {
      idx_out[((size_t)b * Ndim + i) * Kdim + lane] = (int)myJ;
      const float4 pj = pts[myJ];
      float ev[6];
      ev[0] = pi.x; ev[1] = pi.y; ev[2] = pi.z;
      ev[3] = pj.x - pi.x; ev[4] = pj.y - pi.y; ev[5] = pj.z - pi.z;
#pragma unroll
      for (int a = 0; a < 6; ++a) acc[a] += ev[a];
      int c = 6;
#pragma unroll
      for (int a = 0; a < 6; ++a)
#pragma unroll
        for (int d = a; d < 6; ++d) { acc[c] += ev[a] * ev[d]; ++c; }
    }
  }

  // Block reduction of the 27 accumulators (builtin-DPP adds; lane63 = sum)
#pragma unroll
  for (int c = 0; c < NPART; ++c) {
    const float v = red_add_f32_l63(acc[c]);
    if (lane == 63) red[w][c] = v;
  }
  __syncthreads();
  if (tid < NPART) {
    const int bid = blockIdx.y * gridDim.x + blockIdx.x;
    float v = 0.0f;
#pragma unroll
    for (int q = 0; q < 8; ++q) v += red[q][tid];
    partials[(size_t)bid * NPART + tid] = v;
  }
}

// ---------------------------------------------------------------------------
// Kernel 2: reduce 2048 partials (f64), fold 6x6 moments through W into
// per-channel BN scale/shift.
// ---------------------------------------------------------------------------
__global__ __launch_bounds__(256) void k2_bnstats(
    const float* __restrict__ partials, const float* __restrict__ W,
    const float* __restrict__ gamma, const float* __restrict__ beta,
    float* __restrict__ ss) {
  __shared__ double stat[NPART];
  __shared__ double red[4];
  const int tid = threadIdx.x;
  const int lane = tid & 63;
  const int w = tid >> 6;

  for (int c = 0; c < NPART; ++c) {
    double v = 0.0;
    for (int p = tid; p < NBLK1; p += 256) v += (double)partials[(size_t)p * NPART + c];
#pragma unroll
    for (int d = 1; d < 64; d <<= 1) v += __shfl_xor(v, d, 64);
    if (lane == 0) red[w] = v;
    __syncthreads();
    if (tid == 0) stat[c] = red[0] + red[1] + red[2] + red[3];
    __syncthreads();
  }

  if (tid < Edim) {
    const double inv = 1.0 / (double)CNT;
    double mu[6];
#pragma unroll
    for (int c = 0; c < 6; ++c) mu[c] = stat[c] * inv;
    double wv[6];
#pragma unroll
    for (int c = 0; c < 6; ++c) wv[c] = (double)W[tid * 6 + c];
    double m = 0.0;
#pragma unroll
    for (int c = 0; c < 6; ++c) m += wv[c] * mu[c];
    double q = 0.0;
    int s = 6;
#pragma unroll
    for (int a = 0; a < 6; ++a)
#pragma unroll
      for (int d = a; d < 6; ++d) {
        q += (a == d ? 1.0 : 2.0) * wv[a] * wv[d] * (stat[s] * inv);
        ++s;
      }
    const double var = q - m * m;
    const double rstd = 1.0 / sqrt(var + 1e-5);
    const float scale = (float)((double)gamma[tid] * rstd);
    const float shift = (float)((double)beta[tid] - m * rstd * (double)gamma[tid]);
    ss[tid] = scale;
    ss[Edim + tid] = shift;
  }
}

// ---------------------------------------------------------------------------
// Kernel 3: recompute h per (b,n,k,e), BN + hardswish, max over k, write
// out[b,e,n] coalesced via LDS transpose. 512 threads; lane = channel e.
// Neighbor index is wave-uniform -> readfirstlane enables scalar loads.
// (verified passing in R8/R10/R11/R12/R13)
// ---------------------------------------------------------------------------
__global__ __launch_bounds__(512) void k3_out(
    const float* __restrict__ xyz, const int* __restrict__ idx,
    const float* __restrict__ W, const float* __restrict__ ss,
    float* __restrict__ out) {
  __shared__ float4 pts[Ndim];   // 32 KiB: {x,y,z,unused}
  __shared__ float sm[128][65];  // 33 KiB
  const int b = blockIdx.y;
  const int n0 = blockIdx.x * 128;
  const int tid = threadIdx.x;
  const int w = tid >> 6;
  const int lane = tid & 63;
  const float* xb = xyz + (size_t)b * Ndim * Cdim;

  float* sp = (float*)&pts[0];
  for (int g = tid; g < Ndim * Cdim; g += 512) {
    sp[(g / 3) * 4 + (g % 3)] = xb[g];
  }
  __syncthreads();

  float wv[6];
#pragma unroll
  for (int c = 0; c < 6; ++c) wv[c] = W[lane * 6 + c];
  const float scale = ss[lane];
  const float shift = ss[Edim + lane];

  for (int s = 0; s < 16; ++s) {
    const int i = n0 + w * 16 + s;
    const float4 pi = pts[i];
    const float hbase = wv[0] * pi.x + wv[1] * pi.y + wv[2] * pi.z;
    const int* ip = idx + ((size_t)b * Ndim + i) * Kdim;
    float m = -INFINITY;
    for (int k = 0; k < Kdim; ++k) {
      const int j = __builtin_amdgcn_readfirstlane(ip[k]);
      const float4 pj = pts[j];
      const float h = hbase + wv[3] * (pj.x - pi.x) + wv[4] * (pj.y - pi.y) +
                      wv[5] * (pj.z - pi.z);
      const float a = h * scale + shift;
      const float r6 = fminf(fmaxf(a + 3.0f, 0.0f), 6.0f);
      const float hs = a * r6 * (1.0f / 6.0f);
      m = fmaxf(m, hs);
    }
    sm[w * 16 + s][lane] = m;
  }
  __syncthreads();

#pragma unroll
  for (int r = 0; r < 8; ++r) {
    const int e = r * 8 + w;
    out[((size_t)b * Edim + e) * Ndim + n0 + lane] = sm[lane][e];
    out[((size_t)b * Edim + e) * Ndim + n0 + 64 + lane] = sm[64 + lane][e];
  }
}

// ---------------------------------------------------------------------------
extern "C" void kernel_launch(void* const* d_in, const int* in_sizes, int n_in,
                              void* d_out, int out_size, void* d_ws, size_t ws_size,
                              hipStream_t stream) {
  const float* xyz = (const float*)d_in[0];
  const float* W = (const float*)d_in[1];
  const float* gamma = (const float*)d_in[2];
  const float* beta = (const float*)d_in[3];
  float* out = (float*)d_out;

  char* ws = (char*)d_ws;
  int* idx = (int*)ws;                                        // 5,242,880 B
  float* partials = (float*)(ws + (size_t)Bdim * Ndim * Kdim * 4);
  float* ss = (float*)(ws + (size_t)Bdim * Ndim * Kdim * 4 + (size_t)NBLK1 * NPART * 4);

  // Output 0: xyz passthrough
  hipMemcpyAsync(out, xyz, (size_t)Bdim * Ndim * Cdim * sizeof(float),
                 hipMemcpyDeviceToDevice, stream);

  k1_knn_stats<<<dim3(Ndim / 32, Bdim), 512, 0, stream>>>(xyz, idx, partials);
  k2_bnstats<<<1, 256, 0, stream>>>(partials, W, gamma, beta, ss);
  k3_out<<<dim3(Ndim / 128, Bdim), 512, 0, stream>>>(
      xyz, idx, W, ss, out + (size_t)Bdim * Ndim * Cdim);
}